// Round 2
// baseline (462.642 us; speedup 1.0000x reference)
//
#include <hip/hip_runtime.h>
#include <hip/hip_bf16.h>
#include <stdint.h>

// Problem constants (from setup_inputs: N=50000, T=401 -> 400 SDE steps, M=64)
#define N_PART  50000
#define HALF_N  25000
#define STEPS   400
#define T_PTS   401
#define CHUNKS  16
#define SPC     (STEPS / CHUNKS)   // 25 steps per chunk
#define BITS_SPLIT 75000u          // threefry counter split: 150000 bits -> two halves

// ---------------- Threefry-2x32 (exact JAX semantics, 20 rounds) ----------------
__device__ __forceinline__ void threefry2x32(uint32_t k0, uint32_t k1,
                                             uint32_t x0, uint32_t x1,
                                             uint32_t& o0, uint32_t& o1) {
  const uint32_t ks2 = k0 ^ k1 ^ 0x1BD11BDAu;
  x0 += k0; x1 += k1;
#define RND(r) { x0 += x1; x1 = (x1 << r) | (x1 >> (32 - r)); x1 ^= x0; }
  RND(13) RND(15) RND(26) RND(6)
  x0 += k1;  x1 += ks2 + 1u;
  RND(17) RND(29) RND(16) RND(24)
  x0 += ks2; x1 += k0 + 2u;
  RND(13) RND(15) RND(26) RND(6)
  x0 += k0;  x1 += k1 + 3u;
  RND(17) RND(29) RND(16) RND(24)
  x0 += k1;  x1 += ks2 + 4u;
  RND(13) RND(15) RND(26) RND(6)
  x0 += ks2; x1 += k0 + 5u;
#undef RND
  o0 = x0; o1 = x1;
}

// ---------------- XLA f32 erfinv (Giles polynomial) ----------------
__device__ __forceinline__ float erfinv32(float x) {
  float w = -log1pf(-x * x);
  float p;
  if (w < 5.0f) {
    w -= 2.5f;
    p = 2.81022636e-08f;
    p = fmaf(p, w, 3.43273939e-07f);
    p = fmaf(p, w, -3.5233877e-06f);
    p = fmaf(p, w, -4.39150654e-06f);
    p = fmaf(p, w, 0.00021858087f);
    p = fmaf(p, w, -0.00125372503f);
    p = fmaf(p, w, -0.00417768164f);
    p = fmaf(p, w, 0.246640727f);
    p = fmaf(p, w, 1.50140941f);
  } else {
    w = sqrtf(w) - 3.0f;
    p = -0.000200214257f;
    p = fmaf(p, w, 0.000100950558f);
    p = fmaf(p, w, 0.00134934322f);
    p = fmaf(p, w, -0.00367342844f);
    p = fmaf(p, w, 0.00573950773f);
    p = fmaf(p, w, -0.0076224613f);
    p = fmaf(p, w, 0.00943887047f);
    p = fmaf(p, w, 1.00167406f);
    p = fmaf(p, w, 2.83297682f);
  }
  return p * x;
}

// bits -> N(0,1) exactly as jax.random.normal(float32)
__device__ __forceinline__ float bits_to_normal(uint32_t bits) {
  const float lo = __uint_as_float(0xBF7FFFFFu);          // nextafter(-1,0) = -(1-2^-24)
  float f = __uint_as_float((bits >> 9) | 0x3F800000u) - 1.0f;  // [0,1)
  float u = fmaf(f, 2.0f, lo);                            // (hi-lo) rounds to exactly 2.0f
  u = fmaxf(lo, u);
  return 1.41421356237309515f * erfinv32(u);              // np.sqrt(2) cast to f32
}

// ---------------- Kernel 0: keys, suffix weights W, zero S ----------------
// 512-thread blocks: threadIdx.x < 400 covers ALL steps (previous bug: 256 threads).
__global__ __launch_bounds__(512) void setup_kernel(
    const int* __restrict__ delta_us, const int* __restrict__ Delta_us,
    const int* __restrict__ dt_us, const int* __restrict__ seed,
    uint2* __restrict__ keys, float* __restrict__ W, float* __restrict__ Sbuf) {
  int idx = blockIdx.x * blockDim.x + threadIdx.x;
  for (int i = idx; i < N_PART * 3; i += gridDim.x * blockDim.x) Sbuf[i] = 0.0f;

  if (blockIdx.x == 0 && threadIdx.x < STEPS) {
    int i = threadIdx.x;
    // fold_in(key(seed), i) = threefry((0,seed),(0,i))
    uint32_t o0, o1;
    threefry2x32(0u, (uint32_t)seed[0], 0u, (uint32_t)i, o0, o1);
    keys[i] = make_uint2(o0, o1);

    // trapezoidal PGSE envelope; constants as f32(int) * f32(1e-6) to mirror JAX weak types
    float u  = (float)dt_us[0]    * 1e-6f;  // rise = dt
    float df = (float)delta_us[0] * 1e-6f;
    float Df = (float)Delta_us[0] * 1e-6f;
    float w = 0.0f;
    for (int t = i + 1; t < T_PTS; ++t) {
      float tm = (float)t * u;
      float c1 = fminf(fmaxf(tm / u, 0.0f), 1.0f);
      float c2 = fminf(fmaxf((tm - df) / u, 0.0f), 1.0f);
      float c3 = fminf(fmaxf((tm - Df) / u, 0.0f), 1.0f);
      float c4 = fminf(fmaxf(((tm - Df) - df) / u, 0.0f), 1.0f);
      w += (c1 - c2) - (c3 - c4);
    }
    W[i] = w;
  }
}

// ---------------- Kernel 1: per particle-pair weighted noise accumulation ----------------
__global__ __launch_bounds__(256) void sde_kernel(const uint2* __restrict__ keys,
                                                  const float* __restrict__ W,
                                                  const float* __restrict__ D_long,
                                                  const float* __restrict__ D_trans,
                                                  const int* __restrict__ dt_us,
                                                  float* __restrict__ Sbuf) {
  int p = blockIdx.x * 256 + threadIdx.x;
  if (p >= HALF_N) return;
  const uint32_t c0 = 3u * (uint32_t)p;
  const int i0 = blockIdx.y * SPC;

  float a0x = 0.f, a0y = 0.f, a0z = 0.f;   // particle p
  float a1x = 0.f, a1y = 0.f, a1z = 0.f;   // particle p + 25000

  for (int i = i0; i < i0 + SPC; ++i) {
    uint2 k = keys[i];
    float w = W[i];
    uint32_t o0, o1;
    threefry2x32(k.x, k.y, c0,      c0 + BITS_SPLIT,      o0, o1);
    a0x = fmaf(w, bits_to_normal(o0), a0x);
    a1x = fmaf(w, bits_to_normal(o1), a1x);
    threefry2x32(k.x, k.y, c0 + 1u, c0 + 1u + BITS_SPLIT, o0, o1);
    a0y = fmaf(w, bits_to_normal(o0), a0y);
    a1y = fmaf(w, bits_to_normal(o1), a1y);
    threefry2x32(k.x, k.y, c0 + 2u, c0 + 2u + BITS_SPLIT, o0, o1);
    a0z = fmaf(w, bits_to_normal(o0), a0z);
    a1z = fmaf(w, bits_to_normal(o1), a1z);
  }

  // sig = sqrt(2*dt*[D_trans, D_trans, D_long]) in f32 (JAX weak-typed)
  float twodt = 2.0f * ((float)dt_us[0] * 1e-6f);
  float st = sqrtf(twodt * D_trans[0]);
  float sl = sqrtf(twodt * D_long[0]);

  atomicAdd(&Sbuf[3 * p + 0], a0x * st);
  atomicAdd(&Sbuf[3 * p + 1], a0y * st);
  atomicAdd(&Sbuf[3 * p + 2], a0z * sl);
  atomicAdd(&Sbuf[3 * (p + HALF_N) + 0], a1x * st);
  atomicAdd(&Sbuf[3 * (p + HALF_N) + 1], a1y * st);
  atomicAdd(&Sbuf[3 * (p + HALF_N) + 2], a1z * sl);
}

// ---------------- Kernel 2: phases -> |mean exp(i phi)| per measurement ----------------
// Output is FLOAT32 (reference output dtype).
__global__ __launch_bounds__(256) void signal_kernel(const float* __restrict__ Sbuf,
                                                     const float* __restrict__ G_amps,
                                                     const float* __restrict__ grad,
                                                     const int* __restrict__ dt_us,
                                                     float* __restrict__ out) {
  int m = blockIdx.x;
  int tid = threadIdx.x;
  float Kf = 267.513e6f * ((float)dt_us[0] * 1e-6f);  // GAMMA*dt in f32
  float Km = Kf * G_amps[m];
  float gx = grad[3 * m + 0], gy = grad[3 * m + 1], gz = grad[3 * m + 2];

  float cs = 0.f, ss = 0.f;
  for (int n = tid; n < N_PART; n += 256) {
    float sx = Sbuf[3 * n + 0], sy = Sbuf[3 * n + 1], sz = Sbuf[3 * n + 2];
    float ph = Km * (gx * sx + gy * sy + gz * sz);
    float s, c;
    __sincosf(ph, &s, &c);
    // use precise sincos to stay close to XLA's cos/sin
    s = sinf(ph); c = cosf(ph);
    cs += c; ss += s;
  }
  // wave64 reduce then cross-wave via LDS
  for (int off = 32; off > 0; off >>= 1) {
    cs += __shfl_down(cs, off);
    ss += __shfl_down(ss, off);
  }
  __shared__ float redc[4], reds[4];
  int lane = tid & 63, wv = tid >> 6;
  if (lane == 0) { redc[wv] = cs; reds[wv] = ss; }
  __syncthreads();
  if (tid == 0) {
    float c = (redc[0] + redc[1] + redc[2] + redc[3]) / (float)N_PART;
    float s = (reds[0] + reds[1] + reds[2] + reds[3]) / (float)N_PART;
    out[m] = sqrtf(c * c + s * s);
  }
}

extern "C" void kernel_launch(void* const* d_in, const int* in_sizes, int n_in,
                              void* d_out, int out_size, void* d_ws, size_t ws_size,
                              hipStream_t stream) {
  const float* G_amps   = (const float*)d_in[0];
  const float* grad     = (const float*)d_in[1];
  const float* D_long   = (const float*)d_in[2];
  const float* D_trans  = (const float*)d_in[3];
  const int*   delta_us = (const int*)d_in[4];
  const int*   Delta_us = (const int*)d_in[5];
  const int*   dt_us    = (const int*)d_in[6];
  const int*   seed     = (const int*)d_in[8];

  // ws layout: keys[400] (uint2, 3200B) | W[400] (1600B) | S[150000] f32 (600000B)
  uint2* keys = (uint2*)d_ws;
  float* W    = (float*)((char*)d_ws + 3200);
  float* Sbuf = (float*)((char*)d_ws + 4800);

  setup_kernel<<<293, 512, 0, stream>>>(delta_us, Delta_us, dt_us, seed, keys, W, Sbuf);
  sde_kernel<<<dim3((HALF_N + 255) / 256, CHUNKS), 256, 0, stream>>>(keys, W, D_long, D_trans, dt_us, Sbuf);
  int M = in_sizes[0];
  signal_kernel<<<M, 256, 0, stream>>>(Sbuf, G_amps, grad, dt_us, (float*)d_out);
}

// Round 3
// 179.124 us; speedup vs baseline: 2.5828x; 2.5828x over previous
//
#include <hip/hip_runtime.h>
#include <stdint.h>

// Problem constants (from setup_inputs: N=50000, T=401 -> 400 SDE steps, M=64)
#define N_PART  50000
#define HALF_N  25000
#define STEPS   400
#define T_PTS   401
#define CHUNKS  20
#define SPC     (STEPS / CHUNKS)     // 20 steps per chunk
#define BITS_SPLIT 75000u            // threefry counter split: 150000 bits -> two halves
#define SDE_BLOCKS 2048              // exactly 8 blocks/CU at 24-ish VGPR
#define NSPLIT  8

// ---------------- Threefry-2x32 (exact JAX semantics, 20 rounds) ----------------
__device__ __forceinline__ void threefry2x32(uint32_t k0, uint32_t k1,
                                             uint32_t x0, uint32_t x1,
                                             uint32_t& o0, uint32_t& o1) {
  const uint32_t ks2 = k0 ^ k1 ^ 0x1BD11BDAu;
  x0 += k0; x1 += k1;
#define RND(r) { x0 += x1; x1 = (x1 << r) | (x1 >> (32 - r)); x1 ^= x0; }
  RND(13) RND(15) RND(26) RND(6)
  x0 += k1;  x1 += ks2 + 1u;
  RND(17) RND(29) RND(16) RND(24)
  x0 += ks2; x1 += k0 + 2u;
  RND(13) RND(15) RND(26) RND(6)
  x0 += k0;  x1 += k1 + 3u;
  RND(17) RND(29) RND(16) RND(24)
  x0 += k1;  x1 += ks2 + 4u;
  RND(13) RND(15) RND(26) RND(6)
  x0 += ks2; x1 += k0 + 5u;
#undef RND
  o0 = x0; o1 = x1;
}

// bits -> N(0,1) as jax.random.normal(float32), with fast cancellation-free log:
// -log1p(-x^2) = -ln2 * log2((1-x)*(1+x));  (1+x) is exact near x=-1 (Sterbenz),
// so the factored product avoids the cancellation log1p exists to fix.
__device__ __forceinline__ float bits_to_normal(uint32_t bits) {
  const float lo = __uint_as_float(0xBF7FFFFFu);                // nextafter(-1,0)
  float f = __uint_as_float((bits >> 9) | 0x3F800000u) - 1.0f;  // [0,1)
  float u = fmaf(f, 2.0f, lo);                                  // uniform in [lo, 1)
  u = fmaxf(lo, u);
  float t = (1.0f - u) * (1.0f + u);                            // = 1 - u^2, no cancellation
  float w = -0.69314718056f * __log2f(t);                       // v_log_f32
  float p;
  if (w < 5.0f) {
    w -= 2.5f;
    p = 2.81022636e-08f;
    p = fmaf(p, w, 3.43273939e-07f);
    p = fmaf(p, w, -3.5233877e-06f);
    p = fmaf(p, w, -4.39150654e-06f);
    p = fmaf(p, w, 0.00021858087f);
    p = fmaf(p, w, -0.00125372503f);
    p = fmaf(p, w, -0.00417768164f);
    p = fmaf(p, w, 0.246640727f);
    p = fmaf(p, w, 1.50140941f);
  } else {
    w = sqrtf(w) - 3.0f;
    p = -0.000200214257f;
    p = fmaf(p, w, 0.000100950558f);
    p = fmaf(p, w, 0.00134934322f);
    p = fmaf(p, w, -0.00367342844f);
    p = fmaf(p, w, 0.00573950773f);
    p = fmaf(p, w, -0.0076224613f);
    p = fmaf(p, w, 0.00943887047f);
    p = fmaf(p, w, 1.00167406f);
    p = fmaf(p, w, 2.83297682f);
  }
  return 1.41421356237309515f * (p * u);
}

// ---------------- Kernel 0: env->suffix W + keys into packed table, zero accums ----------------
__global__ __launch_bounds__(512) void setup_kernel(
    const int* __restrict__ delta_us, const int* __restrict__ Delta_us,
    const int* __restrict__ dt_us, const int* __restrict__ seed,
    uint4* __restrict__ kw, float* __restrict__ Sbuf, float* __restrict__ acc) {
  __shared__ float env_s[T_PTS];
  int tid = threadIdx.x;

  if (blockIdx.x == 0) {
    if (tid < T_PTS) {
      float u  = (float)dt_us[0]    * 1e-6f;   // rise = dt
      float df = (float)delta_us[0] * 1e-6f;
      float Df = (float)Delta_us[0] * 1e-6f;
      float tm = (float)tid * u;
      float c1 = fminf(fmaxf(tm / u, 0.0f), 1.0f);
      float c2 = fminf(fmaxf((tm - df) / u, 0.0f), 1.0f);
      float c3 = fminf(fmaxf((tm - Df) / u, 0.0f), 1.0f);
      float c4 = fminf(fmaxf(((tm - Df) - df) / u, 0.0f), 1.0f);
      env_s[tid] = (c1 - c2) - (c3 - c4);
    }
    __syncthreads();
    if (tid < STEPS) {
      float w = 0.0f;
      for (int t = tid + 1; t < T_PTS; ++t) w += env_s[t];
      uint32_t o0, o1;  // fold_in(key(seed), i) = threefry((0,seed),(0,i))
      threefry2x32(0u, (uint32_t)seed[0], 0u, (uint32_t)tid, o0, o1);
      kw[tid] = make_uint4(o0, o1, __float_as_uint(w), 0u);
    }
  }
  // zero S buffer and the 128 partial-sum accumulators
  for (int i = blockIdx.x * blockDim.x + tid; i < N_PART * 3; i += gridDim.x * blockDim.x)
    Sbuf[i] = 0.0f;
  if (blockIdx.x == 1 && tid < 128) acc[tid] = 0.0f;
}

// ---------------- Kernel 1: per particle-pair weighted noise accumulation ----------------
__global__ __launch_bounds__(256) void sde_kernel(const uint4* __restrict__ kw,
                                                  const float* __restrict__ D_long,
                                                  const float* __restrict__ D_trans,
                                                  const int* __restrict__ dt_us,
                                                  float* __restrict__ Sbuf) {
  uint32_t tid = blockIdx.x * 256 + threadIdx.x;
  uint32_t chunk = tid / HALF_N;           // 20 chunks x 25000 pairs = 500000 work items
  uint32_t p = tid - chunk * HALF_N;
  if (chunk >= CHUNKS) return;
  const uint32_t c0 = 3u * p;
  const int i0 = (int)chunk * SPC;

  float a0x = 0.f, a0y = 0.f, a0z = 0.f;   // particle p
  float a1x = 0.f, a1y = 0.f, a1z = 0.f;   // particle p + 25000

  for (int s = 0; s < SPC; ++s) {
    uint4 k = kw[i0 + s];
    float w = __uint_as_float(k.z);
    uint32_t o0, o1;
    threefry2x32(k.x, k.y, c0,      c0 + BITS_SPLIT,      o0, o1);
    a0x = fmaf(w, bits_to_normal(o0), a0x);
    a1x = fmaf(w, bits_to_normal(o1), a1x);
    threefry2x32(k.x, k.y, c0 + 1u, c0 + 1u + BITS_SPLIT, o0, o1);
    a0y = fmaf(w, bits_to_normal(o0), a0y);
    a1y = fmaf(w, bits_to_normal(o1), a1y);
    threefry2x32(k.x, k.y, c0 + 2u, c0 + 2u + BITS_SPLIT, o0, o1);
    a0z = fmaf(w, bits_to_normal(o0), a0z);
    a1z = fmaf(w, bits_to_normal(o1), a1z);
  }

  float twodt = 2.0f * ((float)dt_us[0] * 1e-6f);
  float st = sqrtf(twodt * D_trans[0]);
  float sl = sqrtf(twodt * D_long[0]);

  atomicAdd(&Sbuf[3 * p + 0], a0x * st);
  atomicAdd(&Sbuf[3 * p + 1], a0y * st);
  atomicAdd(&Sbuf[3 * p + 2], a0z * sl);
  atomicAdd(&Sbuf[3 * (p + HALF_N) + 0], a1x * st);
  atomicAdd(&Sbuf[3 * (p + HALF_N) + 1], a1y * st);
  atomicAdd(&Sbuf[3 * (p + HALF_N) + 2], a1z * sl);
}

// ---------------- Kernel 2: partial cos/sin sums per (measurement, particle-split) ----------------
__global__ __launch_bounds__(256) void signal_partial(const float* __restrict__ Sbuf,
                                                      const float* __restrict__ G_amps,
                                                      const float* __restrict__ grad,
                                                      const int* __restrict__ dt_us,
                                                      float* __restrict__ acc) {
  int m = blockIdx.x;
  int n0 = blockIdx.y * (N_PART / NSPLIT);
  int tid = threadIdx.x;
  float Kf = 267.513e6f * ((float)dt_us[0] * 1e-6f);
  float Km = Kf * G_amps[m];
  float gx = grad[3 * m + 0], gy = grad[3 * m + 1], gz = grad[3 * m + 2];

  float cs = 0.f, ss = 0.f;
  for (int n = n0 + tid; n < n0 + N_PART / NSPLIT; n += 256) {
    float sx = Sbuf[3 * n + 0], sy = Sbuf[3 * n + 1], sz = Sbuf[3 * n + 2];
    float ph = Km * (gx * sx + gy * sy + gz * sz);
    float s, c;
    __sincosf(ph, &s, &c);                 // v_sin_f32 / v_cos_f32
    cs += c; ss += s;
  }
  for (int off = 32; off > 0; off >>= 1) {
    cs += __shfl_down(cs, off);
    ss += __shfl_down(ss, off);
  }
  __shared__ float redc[4], reds[4];
  int lane = tid & 63, wv = tid >> 6;
  if (lane == 0) { redc[wv] = cs; reds[wv] = ss; }
  __syncthreads();
  if (tid == 0) {
    atomicAdd(&acc[m],      redc[0] + redc[1] + redc[2] + redc[3]);
    atomicAdd(&acc[64 + m], reds[0] + reds[1] + reds[2] + reds[3]);
  }
}

// ---------------- Kernel 3: finalize |mean| (float32 output) ----------------
__global__ void finalize_kernel(const float* __restrict__ acc, float* __restrict__ out, int M) {
  int m = threadIdx.x;
  if (m < M) {
    float c = acc[m] / (float)N_PART;
    float s = acc[64 + m] / (float)N_PART;
    out[m] = sqrtf(c * c + s * s);
  }
}

extern "C" void kernel_launch(void* const* d_in, const int* in_sizes, int n_in,
                              void* d_out, int out_size, void* d_ws, size_t ws_size,
                              hipStream_t stream) {
  const float* G_amps   = (const float*)d_in[0];
  const float* grad     = (const float*)d_in[1];
  const float* D_long   = (const float*)d_in[2];
  const float* D_trans  = (const float*)d_in[3];
  const int*   delta_us = (const int*)d_in[4];
  const int*   Delta_us = (const int*)d_in[5];
  const int*   dt_us    = (const int*)d_in[6];
  const int*   seed     = (const int*)d_in[8];

  // ws layout: kw[400] uint4 (6400B) | S[150000] f32 (600000B) | acc[128] f32 (512B)
  uint4* kw   = (uint4*)d_ws;
  float* Sbuf = (float*)((char*)d_ws + 6400);
  float* acc  = (float*)((char*)d_ws + 6400 + 600000);

  setup_kernel<<<294, 512, 0, stream>>>(delta_us, Delta_us, dt_us, seed, kw, Sbuf, acc);
  sde_kernel<<<SDE_BLOCKS, 256, 0, stream>>>(kw, D_long, D_trans, dt_us, Sbuf);
  int M = in_sizes[0];
  signal_partial<<<dim3(M, NSPLIT), 256, 0, stream>>>(Sbuf, G_amps, grad, dt_us, acc);
  finalize_kernel<<<1, 64, 0, stream>>>(acc, (float*)d_out, M);
}